// Round 8
// baseline (328.270 us; speedup 1.0000x reference)
//
#include <hip/hip_runtime.h>
#include <hip/hip_bf16.h>
#include <math.h>

typedef unsigned short ushort_t;
typedef __bf16 bf16x8 __attribute__((ext_vector_type(8)));
typedef float  f32x4  __attribute__((ext_vector_type(4)));

#define B_SZ   1024
#define SEQ    17
#define KVN    16
#define HDIM   256
#define NHEAD  8
#define DH     32
#define INF    150
#define OUTD   22
#define LN_EPS 1e-5f
#define N1     (B_SZ * SEQ)      // 17408
#define NN_    100000
#define NKVBLK 3125              // 100000 / 32
#define NHQBLK 544               // 17408 / 32

// ---------------- workspace layout (bytes) ----------------
constexpr size_t SZ_H0    = (size_t)NN_ * 256 * 2;
constexpr size_t SZ_KV0   = (size_t)NN_ * 512 * 2;
constexpr size_t SZ_ROW   = (size_t)N1 * 256 * 2;
constexpr size_t OFF_HQ   = 0;
constexpr size_t OFF_KV0  = OFF_HQ + SZ_H0;
constexpr size_t OFF_QKV1 = OFF_KV0;                       // alias (KV0 dead after A0)
constexpr size_t OFF_O1   = OFF_QKV1 + (size_t)N1 * 768 * 2;
constexpr size_t OFF_H2   = OFF_O1 + (size_t)B_SZ * 256 * 2;
constexpr size_t OFF_Q0   = OFF_KV0 + SZ_KV0;
constexpr size_t OFF_O0   = OFF_Q0 + SZ_ROW;
constexpr size_t OFF_H1   = OFF_O0;                        // alias (o0 dead after FFN0 stage)
constexpr size_t OFF_IDS  = OFF_O0 + SZ_ROW;
constexpr size_t OFF_WTIN = OFF_IDS + (size_t)N1 * 4;
constexpr size_t OFF_WKV0 = OFF_WTIN + 256 * 160 * 2;
constexpr size_t OFF_WQ0  = OFF_WKV0 + 512 * 256 * 2;
constexpr size_t OFF_WKVQ1= OFF_WQ0 + 256 * 256 * 2;
constexpr size_t OFF_WO0  = OFF_WKVQ1 + 768 * 256 * 2;
constexpr size_t OFF_WF0  = OFF_WO0 + 256 * 256 * 2;
constexpr size_t OFF_WO1  = OFF_WF0 + 256 * 256 * 2;
constexpr size_t OFF_WF1  = OFF_WO1 + 256 * 256 * 2;
constexpr size_t OFF_B1   = OFF_WF1 + 256 * 256 * 2;

__device__ __forceinline__ ushort_t f2bfu(float x) {
    __hip_bfloat16 h = __float2bfloat16(x);
    return *reinterpret_cast<ushort_t*>(&h);
}
__device__ __forceinline__ float bfu2f(ushort_t u) {
    __hip_bfloat16 h;
    *reinterpret_cast<ushort_t*>(&h) = u;
    return __bfloat162float(h);
}
__device__ __forceinline__ f32x4 mfma16(bf16x8 a, bf16x8 b, f32x4 c) {
    return __builtin_amdgcn_mfma_f32_16x16x32_bf16(a, b, c, 0, 0, 0);
}

// ---------------- prep (unchanged) ----------------
__global__ __launch_bounds__(256) void k_prep(
    const float* __restrict__ W_in, const float* __restrict__ Wqkv,
    const float* __restrict__ Wo, const float* __restrict__ Wf,
    const float* __restrict__ bqkv,
    const int* __restrict__ batch, const int* __restrict__ nbr2,
    char* __restrict__ ws) {
    const int job = blockIdx.y;
    const int idx = blockIdx.x * 256 + threadIdx.x;
    if (job == 11) {
        if (idx < N1) {
            int b = idx / SEQ, s = idx % SEQ;
            ((int*)(ws + OFF_IDS))[idx] = (s == 0) ? batch[b] : nbr2[b * KVN + s - 1];
        }
        return;
    }
    if (job == 12) {
        if (idx < 768) ((float*)(ws + OFF_B1))[idx] = bqkv[768 + ((idx + 256) % 768)];
        return;
    }
    const float* src = nullptr; ushort_t* dst = nullptr;
    int Kpad = 256, Kvalid = 256;
    switch (job) {
        case 0:  src = W_in;           dst = (ushort_t*)(ws + OFF_WTIN); Kpad = 160; Kvalid = 150; break;
        case 1:  src = Wqkv + 65536;   dst = (ushort_t*)(ws + OFF_WKV0); break;
        case 2:  src = Wqkv + 131072;  dst = (ushort_t*)(ws + OFF_WKV0) + 65536; break;
        case 3:  src = Wqkv;           dst = (ushort_t*)(ws + OFF_WQ0); break;
        case 4:  src = Wqkv + 262144;  dst = (ushort_t*)(ws + OFF_WKVQ1); break;
        case 5:  src = Wqkv + 327680;  dst = (ushort_t*)(ws + OFF_WKVQ1) + 65536; break;
        case 6:  src = Wqkv + 196608;  dst = (ushort_t*)(ws + OFF_WKVQ1) + 131072; break;
        case 7:  src = Wo;             dst = (ushort_t*)(ws + OFF_WO0); break;
        case 8:  src = Wo + 65536;     dst = (ushort_t*)(ws + OFF_WO1); break;
        case 9:  src = Wf;             dst = (ushort_t*)(ws + OFF_WF0); break;
        case 10: src = Wf + 65536;     dst = (ushort_t*)(ws + OFF_WF1); break;
    }
    const int total = 256 * Kpad;
    if (idx >= total) return;
    int n = idx / Kpad, k = idx % Kpad;
    dst[idx] = (k < Kvalid) ? f2bfu(src[(size_t)k * 256 + n]) : (ushort_t)0;
}

// ============== fused: kv0 (blocks 0..3124) + hq/q0 (blocks 3125..3668) ======
// 32-row M-tile, 25.6 KB LDS (6 blocks/CU), low-VGPR K-loops (depth-1 prefetch)
__global__ __launch_bounds__(256) void k_fused(
    const float* __restrict__ nf,
    const ushort_t* __restrict__ Wt_in, const float* __restrict__ b_in,
    const ushort_t* __restrict__ Wkv, const ushort_t* __restrict__ Wq,
    const float* __restrict__ bqkv, const int* __restrict__ ids1,
    ushort_t* __restrict__ kv0, ushort_t* __restrict__ hq,
    ushort_t* __restrict__ q0) {
    __shared__ ushort_t Ah[32 * 256];        // 16 KB; XOR-swizzled A tile
    __shared__ ushort_t Sh[4][16][72];       // 9.2 KB; wave-private epilogue bounce
    const int tid = threadIdx.x;
    const bool iskv = blockIdx.x < NKVBLK;
    const int m0 = (iskv ? blockIdx.x : blockIdx.x - NKVBLK) * 32;
    const int lane = tid & 63, w = tid >> 6;
    const int lr = lane & 15, q4 = lane >> 4, lk = q4 * 8;

    // ---- stage A: 32 rows x 160 cols f32->bf16 into Astage (aliases Ah) ----
    {
        ushort_t (*Astage)[168] = reinterpret_cast<ushort_t (*)[168]>(Ah);
        #pragma unroll
        for (int i = 0; i < 3; ++i) {
            int flat = tid + i * 256;                 // 640 chunks = 32 rows x 20
            if (flat < 640) {
                int row = flat / 20, ch = flat % 20;
                int gm = iskv ? (m0 + row) : ids1[m0 + row];
                const float* ap = nf + (size_t)gm * INF + ch * 8;
                ushort_t tmp[8];
                if (ch < 18) {
                    #pragma unroll
                    for (int j = 0; j < 4; ++j) {
                        float2 f = *reinterpret_cast<const float2*>(ap + j * 2);
                        tmp[j * 2] = f2bfu(f.x); tmp[j * 2 + 1] = f2bfu(f.y);
                    }
                } else {
                    #pragma unroll
                    for (int j = 0; j < 8; ++j) {
                        int k = ch * 8 + j;
                        tmp[j] = (k < INF) ? f2bfu(ap[j]) : (ushort_t)0;
                    }
                }
                *reinterpret_cast<int4*>(&Astage[row][ch * 8]) = *reinterpret_cast<int4*>(tmp);
            }
        }
    }
    __syncthreads();

    // ---- phase 1: acc = A @ W_in (K=160), depth-1 B prefetch ----
    f32x4 acc1[2][4] = {};
    {
        ushort_t (*Astage)[168] = reinterpret_cast<ushort_t (*)[168]>(Ah);
        const ushort_t* b0 = Wt_in + (size_t)(w * 64 + 0 * 16 + lr) * 160 + lk;
        const ushort_t* b1 = Wt_in + (size_t)(w * 64 + 1 * 16 + lr) * 160 + lk;
        const ushort_t* b2 = Wt_in + (size_t)(w * 64 + 2 * 16 + lr) * 160 + lk;
        const ushort_t* b3 = Wt_in + (size_t)(w * 64 + 3 * 16 + lr) * 160 + lk;
        bf16x8 bc[4], bn[4];
        bc[0] = *reinterpret_cast<const bf16x8*>(b0);
        bc[1] = *reinterpret_cast<const bf16x8*>(b1);
        bc[2] = *reinterpret_cast<const bf16x8*>(b2);
        bc[3] = *reinterpret_cast<const bf16x8*>(b3);
        #pragma unroll
        for (int s = 0; s < 5; ++s) {
            if (s < 4) {
                bn[0] = *reinterpret_cast<const bf16x8*>(b0 + (s + 1) * 32);
                bn[1] = *reinterpret_cast<const bf16x8*>(b1 + (s + 1) * 32);
                bn[2] = *reinterpret_cast<const bf16x8*>(b2 + (s + 1) * 32);
                bn[3] = *reinterpret_cast<const bf16x8*>(b3 + (s + 1) * 32);
            }
            bf16x8 a0 = *reinterpret_cast<const bf16x8*>(&Astage[lr][s * 32 + lk]);
            bf16x8 a1 = *reinterpret_cast<const bf16x8*>(&Astage[16 + lr][s * 32 + lk]);
            #pragma unroll
            for (int ni = 0; ni < 4; ++ni) {
                acc1[0][ni] = mfma16(a0, bc[ni], acc1[0][ni]);
                acc1[1][ni] = mfma16(a1, bc[ni], acc1[1][ni]);
            }
            if (s < 4) {
                #pragma unroll
                for (int ni = 0; ni < 4; ++ni) bc[ni] = bn[ni];
            }
        }
    }
    __syncthreads();          // Astage reads done before Ah overwrite

    // ---- bias + relu -> Ah (XOR-swizzled) ----
    #pragma unroll
    for (int ni = 0; ni < 4; ++ni) {
        int col = w * 64 + ni * 16 + lr;
        float bb = b_in[col];
        #pragma unroll
        for (int mi = 0; mi < 2; ++mi)
            #pragma unroll
            for (int r = 0; r < 4; ++r) {
                int row = mi * 16 + q4 * 4 + r;
                Ah[row * 256 + (col ^ ((row & 7) << 3))] =
                    f2bfu(fmaxf(acc1[mi][ni][r] + bb, 0.f));
            }
    }
    __syncthreads();

    if (!iskv) {   // persist gathered relu tile for FFN0 residual
        #pragma unroll
        for (int i = 0; i < 4; ++i) {
            int flat = tid + i * 256;                  // 1024 = 32 rows x 32 chunks
            int row = flat >> 5, ch = flat & 31;
            *reinterpret_cast<int4*>(hq + (size_t)(m0 + row) * 256 + ch * 8) =
                *reinterpret_cast<const int4*>(&Ah[row * 256 + ((ch ^ (row & 7)) * 8)]);
        }
    }

    // ---- phase 2: out = Ah @ B (K=256), depth-1 B prefetch ----
    const int npass = iskv ? 2 : 1;
    for (int h = 0; h < npass; ++h) {
        const ushort_t* Bm = iskv ? (Wkv + (size_t)h * 65536) : Wq;
        const float* bias = iskv ? (bqkv + 256 + h * 256) : bqkv;
        const ushort_t* b0 = Bm + (size_t)(w * 64 + 0 * 16 + lr) * 256 + lk;
        const ushort_t* b1 = Bm + (size_t)(w * 64 + 1 * 16 + lr) * 256 + lk;
        const ushort_t* b2 = Bm + (size_t)(w * 64 + 2 * 16 + lr) * 256 + lk;
        const ushort_t* b3 = Bm + (size_t)(w * 64 + 3 * 16 + lr) * 256 + lk;
        f32x4 acc2[2][4] = {};
        bf16x8 bc[4], bn[4];
        bc[0] = *reinterpret_cast<const bf16x8*>(b0);
        bc[1] = *reinterpret_cast<const bf16x8*>(b1);
        bc[2] = *reinterpret_cast<const bf16x8*>(b2);
        bc[3] = *reinterpret_cast<const bf16x8*>(b3);
        #pragma unroll
        for (int s = 0; s < 8; ++s) {
            if (s < 7) {
                bn[0] = *reinterpret_cast<const bf16x8*>(b0 + (s + 1) * 32);
                bn[1] = *reinterpret_cast<const bf16x8*>(b1 + (s + 1) * 32);
                bn[2] = *reinterpret_cast<const bf16x8*>(b2 + (s + 1) * 32);
                bn[3] = *reinterpret_cast<const bf16x8*>(b3 + (s + 1) * 32);
            }
            bf16x8 a0, a1;
            {
                int row0 = lr;
                int ck0 = (s * 4 + q4) ^ (row0 & 7);
                a0 = *reinterpret_cast<const bf16x8*>(&Ah[row0 * 256 + ck0 * 8]);
                int row1 = 16 + lr;
                int ck1 = (s * 4 + q4) ^ (row1 & 7);
                a1 = *reinterpret_cast<const bf16x8*>(&Ah[row1 * 256 + ck1 * 8]);
            }
            #pragma unroll
            for (int ni = 0; ni < 4; ++ni) {
                acc2[0][ni] = mfma16(a0, bc[ni], acc2[0][ni]);
                acc2[1][ni] = mfma16(a1, bc[ni], acc2[1][ni]);
            }
            if (s < 7) {
                #pragma unroll
                for (int ni = 0; ni < 4; ++ni) bc[ni] = bn[ni];
            }
        }
        float bl[4];
        #pragma unroll
        for (int ni = 0; ni < 4; ++ni) bl[ni] = bias[w * 64 + ni * 16 + lr];
        ushort_t* outp = iskv ? kv0 : q0;
        const int ldo = iskv ? 512 : 256;
        const int coff = (iskv ? h * 256 : 0) + w * 64;
        #pragma unroll
        for (int part = 0; part < 2; ++part) {
            #pragma unroll
            for (int ni = 0; ni < 4; ++ni)
                #pragma unroll
                for (int r = 0; r < 4; ++r)
                    Sh[w][q4 * 4 + r][ni * 16 + lr] =
                        f2bfu(acc2[part][ni][r] + bl[ni]);
            #pragma unroll
            for (int j = 0; j < 2; ++j) {
                int flat = lane + j * 64;              // 128 = 16 rows x 8 chunks
                int row = flat >> 3, ch = flat & 7;
                *reinterpret_cast<int4*>(
                    outp + (size_t)(m0 + part * 16 + row) * ldo + coff + ch * 8) =
                    *reinterpret_cast<const int4*>(&Sh[w][row][ch * 8]);
            }
        }
    }
}

// ======= k_ffn (unchanged from r7) =======
__global__ __launch_bounds__(256) void k_ffn(
    const ushort_t* __restrict__ Ain, const ushort_t* __restrict__ W1t,
    const float* __restrict__ b1,
    const ushort_t* __restrict__ resmat, int rstride,
    const float* __restrict__ lng1, const float* __restrict__ lnb1,
    const ushort_t* __restrict__ W2t, const float* __restrict__ b2,
    const float* __restrict__ lng2, const float* __restrict__ lnb2,
    ushort_t* __restrict__ out) {
    __shared__ ushort_t Al[32][264];
    __shared__ float xr[32][260];
    __shared__ float mrow[32], rrow[32];
    const int tid = threadIdx.x;
    const int m0 = blockIdx.x * 32;
    const int lane = tid & 63, w = tid >> 6;
    const int lr = lane & 15, q4 = lane >> 4, lk = q4 * 8;

    #pragma unroll
    for (int j = 0; j < 4; ++j) {
        int flat = tid + j * 256;
        int row = flat >> 5, ch = flat & 31;
        *reinterpret_cast<int4*>(&Al[row][ch * 8]) =
            *reinterpret_cast<const int4*>(Ain + (size_t)(m0 + row) * 256 + ch * 8);
    }
    __syncthreads();

    f32x4 acc[2][4];
    #pragma unroll
    for (int g = 0; g < 2; ++g) {
        const ushort_t* Wt = g ? W2t : W1t;
        #pragma unroll
        for (int mi = 0; mi < 2; ++mi)
            #pragma unroll
            for (int ni = 0; ni < 4; ++ni) acc[mi][ni] = f32x4{0.f, 0.f, 0.f, 0.f};
        bf16x8 bc[4];
        #pragma unroll
        for (int ni = 0; ni < 4; ++ni)
            bc[ni] = *reinterpret_cast<const bf16x8*>(
                Wt + (size_t)(w * 64 + ni * 16 + lr) * 256 + lk);
        #pragma unroll
        for (int s = 0; s < 8; ++s) {
            bf16x8 bn[4];
            if (s < 7) {
                #pragma unroll
                for (int ni = 0; ni < 4; ++ni)
                    bn[ni] = *reinterpret_cast<const bf16x8*>(
                        Wt + (size_t)(w * 64 + ni * 16 + lr) * 256 + (s + 1) * 32 + lk);
            }
            bf16x8 a0 = *reinterpret_cast<const bf16x8*>(&Al[lr][s * 32 + lk]);
            bf16x8 a1 = *reinterpret_cast<const bf16x8*>(&Al[16 + lr][s * 32 + lk]);
            #pragma unroll
            for (int ni = 0; ni < 4; ++ni) {
                acc[0][ni] = mfma16(a0, bc[ni], acc[0][ni]);
                acc[1][ni] = mfma16(a1, bc[ni], acc[1][ni]);
            }
            if (s < 7) {
                #pragma unroll
                for (int ni = 0; ni < 4; ++ni) bc[ni] = bn[ni];
            }
        }
        #pragma unroll
        for (int mi = 0; mi < 2; ++mi)
            #pragma unroll
            for (int ni = 0; ni < 4; ++ni)
                #pragma unroll
                for (int r = 0; r < 4; ++r)
                    xr[mi * 16 + q4 * 4 + r][w * 64 + ni * 16 + lr] = acc[mi][ni][r];
        __syncthreads();
        {
            float bb = g ? b2[tid] : b1[tid];
            if (g == 0) {
                for (int r = 0; r < 32; ++r)
                    xr[r][tid] += bb + bfu2f(resmat[(size_t)(m0 + r) * rstride * 256 + tid]);
            } else {
                for (int r = 0; r < 32; ++r)
                    xr[r][tid] += bb + bfu2f(Al[r][tid]);
            }
        }
        __syncthreads();
        for (int rr = w * 8; rr < w * 8 + 8; ++rr) {
            float4 v = *reinterpret_cast<const float4*>(&xr[rr][lane * 4]);
            float s1 = v.x + v.y + v.z + v.w;
            float s2 = v.x * v.x + v.y * v.y + v.z * v.z + v.w * v.w;
            #pragma unroll
            for (int off = 32; off > 0; off >>= 1) {
                s1 += __shfl_xor(s1, off);
                s2 += __shfl_xor(s2, off);
            }
            if (lane == 0) {
                float m = s1 * (1.f / 256.f);
                float var = s2 * (1.f / 256.f) - m * m;
                mrow[rr] = m;
                rrow[rr] = rsqrtf(var + LN_EPS);
            }
        }
        __syncthreads();
        if (g == 0) {
            float gg = lng1[tid], bb = lnb1[tid];
            for (int r = 0; r < 32; ++r)
                Al[r][tid] = f2bfu((xr[r][tid] - mrow[r]) * rrow[r] * gg + bb);
        } else {
            float gg = lng2[tid], bb = lnb2[tid];
            for (int r = 0; r < 32; ++r)
                out[(size_t)(m0 + r) * 256 + tid] =
                    f2bfu((xr[r][tid] - mrow[r]) * rrow[r] * gg + bb);
        }
        __syncthreads();
    }
}

// ======= k_qkv1 (unchanged from r7) =======
__global__ __launch_bounds__(256) void k_qkv1(
    const ushort_t* __restrict__ h1, const ushort_t* __restrict__ Wt,
    const float* __restrict__ bias, ushort_t* __restrict__ outm) {
    __shared__ ushort_t Ah[64 * 256];
    __shared__ ushort_t Sh[4][32][72];
    const int tid = threadIdx.x;
    const int m0 = blockIdx.x * 64;
    const int lane = tid & 63, w = tid >> 6;
    const int lr = lane & 15, q4 = lane >> 4, lk = q4 * 8;

    #pragma unroll
    for (int i = 0; i < 8; ++i) {
        int flat = tid + i * 256;
        int row = flat >> 5, ch = flat & 31;
        *reinterpret_cast<int4*>(&Ah[row * 256 + ((ch ^ (row & 7)) * 8)]) =
            *reinterpret_cast<const int4*>(h1 + (size_t)(m0 + row) * 256 + ch * 8);
    }
    __syncthreads();

    for (int p = 0; p < 3; ++p) {
        f32x4 acc[4][4] = {};
        bf16x8 bc[4];
        #pragma unroll
        for (int ni = 0; ni < 4; ++ni)
            bc[ni] = *reinterpret_cast<const bf16x8*>(
                Wt + (size_t)(p * 256 + w * 64 + ni * 16 + lr) * 256 + lk);
        #pragma unroll
        for (int s = 0; s < 8; ++s) {
            bf16x8 bn[4];
            if (s < 7) {
                #pragma unroll
                for (int ni = 0; ni < 4; ++ni)
                    bn[ni] = *reinterpret_cast<const bf16x8*>(
                        Wt + (size_t)(p * 256 + w * 64 + ni * 16 + lr) * 256 + (s + 1) * 32 + lk);
            }
            bf16x8 a[4];
            #pragma unroll
            for (int mi = 0; mi < 4; ++mi) {
                int row = mi * 16 + lr;
                int chunk = (s * 4 + q4) ^ (row & 7);
                a[mi] = *reinterpret_cast<const bf16x8*>(&Ah[row * 256 + chunk * 8]);
            }
            #pragma unroll
            for (int mi = 0; mi < 4; ++mi)
                #pragma unroll
                for (int ni = 0; ni < 4; ++ni)
                    acc[mi][ni] = mfma16(a[mi], bc[ni], acc[mi][ni]);
            if (s < 7) {
                #pragma unroll
                for (int ni = 0; ni < 4; ++ni) bc[ni] = bn[ni];
            }
        }
        float bl[4];
        #pragma unroll
        for (int ni = 0; ni < 4; ++ni) bl[ni] = bias[p * 256 + w * 64 + ni * 16 + lr];
        const int coff = p * 256 + w * 64;
        #pragma unroll
        for (int part = 0; part < 2; ++part) {
            #pragma unroll
            for (int mi2 = 0; mi2 < 2; ++mi2) {
                int mi = part * 2 + mi2;
                #pragma unroll
                for (int ni = 0; ni < 4; ++ni)
                    #pragma unroll
                    for (int r = 0; r < 4; ++r)
                        Sh[w][mi2 * 16 + q4 * 4 + r][ni * 16 + lr] =
                            f2bfu(acc[mi][ni][r] + bl[ni]);
            }
            #pragma unroll
            for (int j = 0; j < 4; ++j) {
                int flat = lane + j * 64;
                int r32 = flat >> 3, ch = flat & 7;
                int grow = m0 + part * 32 + r32;
                *reinterpret_cast<int4*>(outm + (size_t)grow * 768 + coff + ch * 8) =
                    *reinterpret_cast<const int4*>(&Sh[w][r32][ch * 8]);
            }
        }
    }
}

// ---------------- attention: one wave per group (unchanged) ----------------
__global__ __launch_bounds__(256) void attn_wave(
    const ushort_t* __restrict__ q_all, int qld, int qoff, int qstride,
    const ushort_t* __restrict__ kv_all, int kvld, int koff, int voff,
    const int* __restrict__ kvidx, int ngroups, ushort_t* __restrict__ o_out) {
    __shared__ ushort_t KL[4][KVN][264];
    __shared__ ushort_t VL[4][KVN][264];
    const int w = threadIdx.x >> 6, lane = threadIdx.x & 63;
    const int g = blockIdx.x * 4 + w;
    if (g >= ngroups) return;

    int idx16 = 0;
    if (lane < KVN)
        idx16 = kvidx ? kvidx[g * KVN + lane] : g * SEQ + 1 + lane;

    float qv[4];
    {
        uint2 u = *reinterpret_cast<const uint2*>(
            q_all + (size_t)g * qstride * qld + qoff + lane * 4);
        qv[0] = bfu2f((ushort_t)(u.x & 0xffff));
        qv[1] = bfu2f((ushort_t)(u.x >> 16));
        qv[2] = bfu2f((ushort_t)(u.y & 0xffff));
        qv[3] = bfu2f((ushort_t)(u.y >> 16));
    }
    {
        const int r = lane & 15, qtr = lane >> 4;
        int rid = __shfl(idx16, r);
        const ushort_t* kb = kv_all + (size_t)rid * kvld + koff;
        const ushort_t* vb = kv_all + (size_t)rid * kvld + voff;
        #pragma unroll
        for (int j = 0; j < 8; ++j) {
            int c8 = (qtr * 8 + j) * 8;
            *reinterpret_cast<int4*>(&KL[w][r][c8]) = *reinterpret_cast<const int4*>(kb + c8);
            *reinterpret_cast<int4*>(&VL[w][r][c8]) = *reinterpret_cast<const int4*>(vb + c8);
        }
    }
    float att[KVN];
    #pragma unroll
    for (int k = 0; k < KVN; ++k) {
        uint2 u = *reinterpret_cast<const uint2*>(&KL[w][k][lane * 4]);
        float p = qv[0] * bfu2f((ushort_t)(u.x & 0xffff))
                + qv[1] * bfu2f((ushort_t)(u.x >> 16))
                + qv[2] * bfu2f((ushort_t)(u.y & 0xffff))
                + qv[3] * bfu2f((ushort_t)(u.y >> 16));
        p += __shfl_xor(p, 1);
        p += __shfl_xor(p, 2);
        p += __shfl_xor(p, 4);
        att[k] = p * 0.17677669529663687f;
    }
    float m = att[0];
    #pragma unroll
    for (int k = 1; k < KVN; ++k) m = fmaxf(m, att[k]);
    float sum = 0.f;
    #pragma unroll
    for (int k = 0; k < KVN; ++k) { att[k] = __expf(att[k] - m); sum += att[k]; }
    float inv = 1.f / sum;
    float o[4] = {0.f, 0.f, 0.f, 0.f};
    #pragma unroll
    for (int k = 0; k < KVN; ++k) {
        uint2 u = *reinterpret_cast<const uint2*>(&VL[w][k][lane * 4]);
        float a = att[k] * inv;
        o[0] += a * bfu2f((ushort_t)(u.x & 0xffff));
        o[1] += a * bfu2f((ushort_t)(u.x >> 16));
        o[2] += a * bfu2f((ushort_t)(u.y & 0xffff));
        o[3] += a * bfu2f((ushort_t)(u.y >> 16));
    }
    uint2 r;
    r.x = (unsigned)f2bfu(o[0]) | ((unsigned)f2bfu(o[1]) << 16);
    r.y = (unsigned)f2bfu(o[2]) | ((unsigned)f2bfu(o[3]) << 16);
    *reinterpret_cast<uint2*>(o_out + (size_t)g * 256 + lane * 4) = r;
}

// ---------------- output head (unchanged) ----------------
__global__ __launch_bounds__(64) void k_out(
    const ushort_t* __restrict__ h2, const float* __restrict__ W_out,
    const float* __restrict__ b_out, float* __restrict__ out) {
    const int b = blockIdx.x, j = threadIdx.x;
    __shared__ float xr[HDIM];
    for (int k = j; k < HDIM; k += 64) xr[k] = bfu2f(h2[(size_t)b * HDIM + k]);
    __syncthreads();
    float logit = -1e30f;
    if (j < OUTD) {
        float acc = b_out[j];
        for (int k = 0; k < HDIM; ++k) acc += xr[k] * W_out[k * OUTD + j];
        logit = acc;
    }
    float m = logit;
    #pragma unroll
    for (int off = 32; off > 0; off >>= 1) m = fmaxf(m, __shfl_xor(m, off));
    float e = (j < OUTD) ? __expf(logit - m) : 0.f;
    float s = e;
    #pragma unroll
    for (int off = 32; off > 0; off >>= 1) s += __shfl_xor(s, off);
    if (j < OUTD) out[(size_t)b * OUTD + j] = e / s;
}

extern "C" void kernel_launch(void* const* d_in, const int* in_sizes, int n_in,
                              void* d_out, int out_size, void* d_ws, size_t ws_size,
                              hipStream_t stream) {
    const float* nf    = (const float*)d_in[0];
    const int*   batch = (const int*)d_in[1];
    const int*   nbr2  = (const int*)d_in[2];
    const int*   nbr1  = (const int*)d_in[3];
    const float* W_in  = (const float*)d_in[4];
    const float* b_in  = (const float*)d_in[5];
    const float* Wqkv  = (const float*)d_in[6];
    const float* bqkv  = (const float*)d_in[7];
    const float* Wo    = (const float*)d_in[8];
    const float* bo    = (const float*)d_in[9];
    const float* Wf    = (const float*)d_in[10];
    const float* bf    = (const float*)d_in[11];
    const float* ln_g  = (const float*)d_in[12];
    const float* ln_b  = (const float*)d_in[13];
    const float* W_out = (const float*)d_in[14];
    const float* b_out = (const float*)d_in[15];
    float* out = (float*)d_out;
    char* ws = (char*)d_ws;

    ushort_t* hq   = (ushort_t*)(ws + OFF_HQ);
    ushort_t* kv0  = (ushort_t*)(ws + OFF_KV0);
    ushort_t* q0   = (ushort_t*)(ws + OFF_Q0);
    ushort_t* o0   = (ushort_t*)(ws + OFF_O0);
    ushort_t* h1   = (ushort_t*)(ws + OFF_H1);
    ushort_t* qkv1 = (ushort_t*)(ws + OFF_QKV1);
    ushort_t* o1   = (ushort_t*)(ws + OFF_O1);
    ushort_t* h2   = (ushort_t*)(ws + OFF_H2);
    const int* ids1 = (const int*)(ws + OFF_IDS);

    hipLaunchKernelGGL(k_prep, dim3(256, 13), dim3(256), 0, stream,
                       W_in, Wqkv, Wo, Wf, bqkv, batch, nbr2, ws);
    hipLaunchKernelGGL(k_fused, dim3(NKVBLK + NHQBLK), dim3(256), 0, stream,
                       nf, (const ushort_t*)(ws + OFF_WTIN), b_in,
                       (const ushort_t*)(ws + OFF_WKV0),
                       (const ushort_t*)(ws + OFF_WQ0), bqkv, ids1,
                       kv0, hq, q0);
    // A0
    hipLaunchKernelGGL(attn_wave, dim3(N1 / 4), dim3(256), 0, stream,
                       q0, 256, 0, 1, kv0, 512, 0, 256, nbr1, N1, o0);
    // FFN0
    hipLaunchKernelGGL(k_ffn, dim3(N1 / 32), dim3(256), 0, stream,
                       o0, (const ushort_t*)(ws + OFF_WO0), bo,
                       hq, 1, ln_g, ln_b,
                       (const ushort_t*)(ws + OFF_WF0), bf,
                       ln_g + 256, ln_b + 256, h1);
    // G5
    hipLaunchKernelGGL(k_qkv1, dim3(N1 / 64), dim3(256), 0, stream,
                       h1, (const ushort_t*)(ws + OFF_WKVQ1),
                       (const float*)(ws + OFF_B1), qkv1);
    // A1
    hipLaunchKernelGGL(attn_wave, dim3(B_SZ / 4), dim3(256), 0, stream,
                       qkv1, 768, 512, 17, qkv1, 768, 0, 256,
                       (const int*)nullptr, B_SZ, o1);
    // FFN1
    hipLaunchKernelGGL(k_ffn, dim3(B_SZ / 32), dim3(256), 0, stream,
                       o1, (const ushort_t*)(ws + OFF_WO1), bo + 256,
                       h1, 17, ln_g + 512, ln_b + 512,
                       (const ushort_t*)(ws + OFF_WF1), bf + 256,
                       ln_g + 768, ln_b + 768, h2);
    hipLaunchKernelGGL(k_out, dim3(B_SZ), dim3(64), 0, stream,
                       h2, W_out, b_out, out);
}

// Round 9
// 275.833 us; speedup vs baseline: 1.1901x; 1.1901x over previous
//
#include <hip/hip_runtime.h>
#include <hip/hip_bf16.h>
#include <math.h>

typedef unsigned short ushort_t;
typedef __bf16 bf16x8 __attribute__((ext_vector_type(8)));
typedef float  f32x4  __attribute__((ext_vector_type(4)));
typedef __attribute__((address_space(1))) const unsigned int* gas_t;
typedef __attribute__((address_space(3))) unsigned int* las_t;

#define B_SZ   1024
#define SEQ    17
#define KVN    16
#define HDIM   256
#define NHEAD  8
#define DH     32
#define INF    150
#define OUTD   22
#define LN_EPS 1e-5f
#define N1     (B_SZ * SEQ)      // 17408
#define NN_    100000
#define NKVBLK 1563              // ceil(100000/64)
#define NHQBLK 272               // 17408 / 64

// ---------------- workspace layout (bytes) ----------------
constexpr size_t SZ_H0    = (size_t)NN_ * 256 * 2;
constexpr size_t SZ_KV0   = (size_t)NN_ * 512 * 2;
constexpr size_t SZ_ROW   = (size_t)N1 * 256 * 2;
constexpr size_t OFF_HQ   = 0;
constexpr size_t OFF_KV0  = OFF_HQ + SZ_H0;
constexpr size_t OFF_QKV1 = OFF_KV0;                       // alias (KV0 dead after A0)
constexpr size_t OFF_O1   = OFF_QKV1 + (size_t)N1 * 768 * 2;
constexpr size_t OFF_H2   = OFF_O1 + (size_t)B_SZ * 256 * 2;
constexpr size_t OFF_Q0   = OFF_KV0 + SZ_KV0;
constexpr size_t OFF_O0   = OFF_Q0 + SZ_ROW;
constexpr size_t OFF_H1   = OFF_O0;                        // alias (o0 dead after FFN0 stage)
constexpr size_t OFF_IDS  = OFF_O0 + SZ_ROW;
constexpr size_t OFF_WTIN = OFF_IDS + (size_t)N1 * 4;
constexpr size_t OFF_WKV0 = OFF_WTIN + 256 * 160 * 2;
constexpr size_t OFF_WQ0  = OFF_WKV0 + 512 * 256 * 2;
constexpr size_t OFF_WKVQ1= OFF_WQ0 + 256 * 256 * 2;
constexpr size_t OFF_WO0  = OFF_WKVQ1 + 768 * 256 * 2;
constexpr size_t OFF_WF0  = OFF_WO0 + 256 * 256 * 2;
constexpr size_t OFF_WO1  = OFF_WF0 + 256 * 256 * 2;
constexpr size_t OFF_WF1  = OFF_WO1 + 256 * 256 * 2;
constexpr size_t OFF_B1   = OFF_WF1 + 256 * 256 * 2;

__device__ __forceinline__ ushort_t f2bfu(float x) {
    __hip_bfloat16 h = __float2bfloat16(x);
    return *reinterpret_cast<ushort_t*>(&h);
}
__device__ __forceinline__ float bfu2f(ushort_t u) {
    __hip_bfloat16 h;
    *reinterpret_cast<ushort_t*>(&h) = u;
    return __bfloat162float(h);
}
__device__ __forceinline__ f32x4 mfma16(bf16x8 a, bf16x8 b, f32x4 c) {
    return __builtin_amdgcn_mfma_f32_16x16x32_bf16(a, b, c, 0, 0, 0);
}

// stage a [256 N-rows][32 K] bf16 tile into LDS via global_load_lds (16B/lane).
// LDS layout: row*64B + q_store*16B, where chunk q_log lives at
// q_store = q_log ^ ((row>>1)&3)  (both-sides swizzle: linear dest,
// pre-swizzled SOURCE here, swizzled ds_read at consume).
__device__ __forceinline__ void stage_b(
    const ushort_t* __restrict__ Bsrc, int Kld, int kk,
    ushort_t* lbase, int w, int lane) {
    #pragma unroll
    for (int i = 0; i < 4; ++i) {
        int inst = w * 4 + i;
        int row = inst * 16 + (lane >> 2);
        int q_log = (lane & 3) ^ ((row >> 1) & 3);
        const ushort_t* src = Bsrc + (size_t)row * Kld + kk + q_log * 8;
        __builtin_amdgcn_global_load_lds((gas_t)(const void*)src,
                                         (las_t)(void*)(lbase + inst * 512),
                                         16, 0, 0);
    }
}

// ---------------- prep (unchanged) ----------------
__global__ __launch_bounds__(256) void k_prep(
    const float* __restrict__ W_in, const float* __restrict__ Wqkv,
    const float* __restrict__ Wo, const float* __restrict__ Wf,
    const float* __restrict__ bqkv,
    const int* __restrict__ batch, const int* __restrict__ nbr2,
    char* __restrict__ ws) {
    const int job = blockIdx.y;
    const int idx = blockIdx.x * 256 + threadIdx.x;
    if (job == 11) {
        if (idx < N1) {
            int b = idx / SEQ, s = idx % SEQ;
            ((int*)(ws + OFF_IDS))[idx] = (s == 0) ? batch[b] : nbr2[b * KVN + s - 1];
        }
        return;
    }
    if (job == 12) {
        if (idx < 768) ((float*)(ws + OFF_B1))[idx] = bqkv[768 + ((idx + 256) % 768)];
        return;
    }
    const float* src = nullptr; ushort_t* dst = nullptr;
    int Kpad = 256, Kvalid = 256;
    switch (job) {
        case 0:  src = W_in;           dst = (ushort_t*)(ws + OFF_WTIN); Kpad = 160; Kvalid = 150; break;
        case 1:  src = Wqkv + 65536;   dst = (ushort_t*)(ws + OFF_WKV0); break;
        case 2:  src = Wqkv + 131072;  dst = (ushort_t*)(ws + OFF_WKV0) + 65536; break;
        case 3:  src = Wqkv;           dst = (ushort_t*)(ws + OFF_WQ0); break;
        case 4:  src = Wqkv + 262144;  dst = (ushort_t*)(ws + OFF_WKVQ1); break;
        case 5:  src = Wqkv + 327680;  dst = (ushort_t*)(ws + OFF_WKVQ1) + 65536; break;
        case 6:  src = Wqkv + 196608;  dst = (ushort_t*)(ws + OFF_WKVQ1) + 131072; break;
        case 7:  src = Wo;             dst = (ushort_t*)(ws + OFF_WO0); break;
        case 8:  src = Wo + 65536;     dst = (ushort_t*)(ws + OFF_WO1); break;
        case 9:  src = Wf;             dst = (ushort_t*)(ws + OFF_WF0); break;
        case 10: src = Wf + 65536;     dst = (ushort_t*)(ws + OFF_WF1); break;
    }
    const int total = 256 * Kpad;
    if (idx >= total) return;
    int n = idx / Kpad, k = idx % Kpad;
    dst[idx] = (k < Kvalid) ? f2bfu(src[(size_t)k * 256 + n]) : (ushort_t)0;
}

// ============== fused: kv0 (blocks 0..1562) + hq/q0 (blocks 1563..1834) ======
// m97-style K-loops: B staged via global_load_lds double-buffer (zero VGPR
// cost), A resident in swizzled LDS, one barrier per K-step.
__global__ __launch_bounds__(256) void k_fused(
    const float* __restrict__ nf,
    const ushort_t* __restrict__ Wt_in, const float* __restrict__ b_in,
    const ushort_t* __restrict__ Wkv, const ushort_t* __restrict__ Wq,
    const float* __restrict__ bqkv, const int* __restrict__ ids1,
    ushort_t* __restrict__ kv0, ushort_t* __restrict__ hq,
    ushort_t* __restrict__ q0) {
    __shared__ ushort_t Ah[64 * 256];        // 32 KB: A tile (XOR-swizzled)
    __shared__ ushort_t Bbuf[2 * 8192];      // 32 KB: B staging dbuf / epilogue
    const int tid = threadIdx.x;
    const bool iskv = blockIdx.x < NKVBLK;
    const int m0 = (iskv ? blockIdx.x : blockIdx.x - NKVBLK) * 64;
    const int lane = tid & 63, w = tid >> 6;
    const int lr = lane & 15, q4 = lane >> 4, lk = q4 * 8;

    // ---- stage A: 64 rows x 160 cols f32->bf16 into Astage (aliases Ah) ----
    {
        ushort_t (*Astage)[168] = reinterpret_cast<ushort_t (*)[168]>(Ah);
        #pragma unroll
        for (int i = 0; i < 5; ++i) {
            int flat = tid + i * 256;             // 1280 chunks = 64 rows x 20
            int row = flat / 20, ch = flat % 20;
            int gm; 
            if (iskv) { gm = m0 + row; if (gm >= NN_) gm = 0; }
            else      { gm = ids1[m0 + row]; }
            const float* ap = nf + (size_t)gm * INF + ch * 8;
            ushort_t tmp[8];
            if (ch < 18) {
                #pragma unroll
                for (int j = 0; j < 4; ++j) {
                    float2 f = *reinterpret_cast<const float2*>(ap + j * 2);
                    tmp[j * 2] = f2bfu(f.x); tmp[j * 2 + 1] = f2bfu(f.y);
                }
            } else {
                #pragma unroll
                for (int j = 0; j < 8; ++j) {
                    int k = ch * 8 + j;
                    tmp[j] = (k < INF) ? f2bfu(ap[j]) : (ushort_t)0;
                }
            }
            *reinterpret_cast<int4*>(&Astage[row][ch * 8]) = *reinterpret_cast<int4*>(tmp);
        }
    }
    // prologue: B tile 0 of phase 1 -> buf0 (fire & forget)
    stage_b(Wt_in, 160, 0, Bbuf, w, lane);
    __syncthreads();          // A visible + vmcnt drained (buf0 ready)

    // ---- phase 1: acc = A @ W_in (K=160, 5 steps), m97 loop ----
    f32x4 acc1[4][4] = {};
    {
        ushort_t (*Astage)[168] = reinterpret_cast<ushort_t (*)[168]>(Ah);
        for (int s = 0; s < 5; ++s) {
            const int cur = s & 1;
            if (s < 4) stage_b(Wt_in, 160, (s + 1) * 32, Bbuf + (cur ^ 1) * 8192, w, lane);
            bf16x8 a[4], b[4];
            #pragma unroll
            for (int mi = 0; mi < 4; ++mi)
                a[mi] = *reinterpret_cast<const bf16x8*>(&Astage[mi * 16 + lr][s * 32 + lk]);
            #pragma unroll
            for (int ni = 0; ni < 4; ++ni) {
                int n = w * 64 + ni * 16 + lr;
                b[ni] = *reinterpret_cast<const bf16x8*>(
                    &Bbuf[cur * 8192 + n * 32 + ((q4 ^ ((n >> 1) & 3)) * 8)]);
            }
            #pragma unroll
            for (int mi = 0; mi < 4; ++mi)
                #pragma unroll
                for (int ni = 0; ni < 4; ++ni)
                    acc1[mi][ni] = mfma16(a[mi], b[ni], acc1[mi][ni]);
            __syncthreads();
        }
    }

    // ---- bias + relu -> Ah (XOR-swizzled) ----
    #pragma unroll
    for (int ni = 0; ni < 4; ++ni) {
        int col = w * 64 + ni * 16 + lr;
        float bb = b_in[col];
        #pragma unroll
        for (int mi = 0; mi < 4; ++mi)
            #pragma unroll
            for (int r = 0; r < 4; ++r) {
                int row = mi * 16 + q4 * 4 + r;
                Ah[row * 256 + (col ^ ((row & 7) << 3))] =
                    f2bfu(fmaxf(acc1[mi][ni][r] + bb, 0.f));
            }
    }
    __syncthreads();

    if (!iskv) {   // persist gathered relu tile for FFN0 residual
        #pragma unroll
        for (int i = 0; i < 8; ++i) {
            int flat = tid + i * 256;
            int row = flat >> 5, ch = flat & 31;
            *reinterpret_cast<int4*>(hq + (size_t)(m0 + row) * 256 + ch * 8) =
                *reinterpret_cast<const int4*>(&Ah[row * 256 + ((ch ^ (row & 7)) * 8)]);
        }
    }

    // ---- phase 2: out = Ah @ B (K=256, 8 steps per pass), m97 loop ----
    const int npass = iskv ? 2 : 1;
    for (int h = 0; h < npass; ++h) {
        const ushort_t* Bm = iskv ? (Wkv + (size_t)h * 65536) : Wq;
        const float* bias = iskv ? (bqkv + 256 + h * 256) : bqkv;
        __syncthreads();                       // all prior Bbuf readers done
        stage_b(Bm, 256, 0, Bbuf, w, lane);    // prologue tile 0 -> buf0
        __syncthreads();                       // vmcnt drained
        f32x4 acc2[4][4] = {};
        for (int s = 0; s < 8; ++s) {
            const int cur = s & 1;
            if (s < 7) stage_b(Bm, 256, (s + 1) * 32, Bbuf + (cur ^ 1) * 8192, w, lane);
            bf16x8 a[4], b[4];
            #pragma unroll
            for (int mi = 0; mi < 4; ++mi) {
                int row = mi * 16 + lr;
                int chunk = (s * 4 + q4) ^ (row & 7);
                a[mi] = *reinterpret_cast<const bf16x8*>(&Ah[row * 256 + chunk * 8]);
            }
            #pragma unroll
            for (int ni = 0; ni < 4; ++ni) {
                int n = w * 64 + ni * 16 + lr;
                b[ni] = *reinterpret_cast<const bf16x8*>(
                    &Bbuf[cur * 8192 + n * 32 + ((q4 ^ ((n >> 1) & 3)) * 8)]);
            }
            #pragma unroll
            for (int mi = 0; mi < 4; ++mi)
                #pragma unroll
                for (int ni = 0; ni < 4; ++ni)
                    acc2[mi][ni] = mfma16(a[mi], b[ni], acc2[mi][ni]);
            __syncthreads();
        }
        // epilogue: bounce through Bbuf (wave-private [32][72] slices)
        float bl[4];
        #pragma unroll
        for (int ni = 0; ni < 4; ++ni) bl[ni] = bias[w * 64 + ni * 16 + lr];
        ushort_t* outp = iskv ? kv0 : q0;
        const int ldo = iskv ? 512 : 256;
        const int coff = (iskv ? h * 256 : 0) + w * 64;
        ushort_t* Shw = Bbuf + w * 32 * 72;
        #pragma unroll
        for (int part = 0; part < 2; ++part) {
            #pragma unroll
            for (int mi2 = 0; mi2 < 2; ++mi2) {
                int mi = part * 2 + mi2;
                #pragma unroll
                for (int ni = 0; ni < 4; ++ni)
                    #pragma unroll
                    for (int r = 0; r < 4; ++r)
                        Shw[(mi2 * 16 + q4 * 4 + r) * 72 + ni * 16 + lr] =
                            f2bfu(acc2[mi][ni][r] + bl[ni]);
            }
            #pragma unroll
            for (int j = 0; j < 4; ++j) {
                int flat = lane + j * 64;              // 256 = 32 rows x 8 chunks
                int r32 = flat >> 3, ch = flat & 7;
                int grow = m0 + part * 32 + r32;
                if (!iskv || grow < NN_)
                    *reinterpret_cast<int4*>(outp + (size_t)grow * ldo + coff + ch * 8) =
                        *reinterpret_cast<const int4*>(&Shw[r32 * 72 + ch * 8]);
            }
        }
    }
}

// ======= k_ffn (unchanged) =======
__global__ __launch_bounds__(256) void k_ffn(
    const ushort_t* __restrict__ Ain, const ushort_t* __restrict__ W1t,
    const float* __restrict__ b1,
    const ushort_t* __restrict__ resmat, int rstride,
    const float* __restrict__ lng1, const float* __restrict__ lnb1,
    const ushort_t* __restrict__ W2t, const float* __restrict__ b2,
    const float* __restrict__ lng2, const float* __restrict__ lnb2,
    ushort_t* __restrict__ out) {
    __shared__ ushort_t Al[32][264];
    __shared__ float xr[32][260];
    __shared__ float mrow[32], rrow[32];
    const int tid = threadIdx.x;
    const int m0 = blockIdx.x * 32;
    const int lane = tid & 63, w = tid >> 6;
    const int lr = lane & 15, q4 = lane >> 4, lk = q4 * 8;

    #pragma unroll
    for (int j = 0; j < 4; ++j) {
        int flat = tid + j * 256;
        int row = flat >> 5, ch = flat & 31;
        *reinterpret_cast<int4*>(&Al[row][ch * 8]) =
            *reinterpret_cast<const int4*>(Ain + (size_t)(m0 + row) * 256 + ch * 8);
    }
    __syncthreads();

    f32x4 acc[2][4];
    #pragma unroll
    for (int g = 0; g < 2; ++g) {
        const ushort_t* Wt = g ? W2t : W1t;
        #pragma unroll
        for (int mi = 0; mi < 2; ++mi)
            #pragma unroll
            for (int ni = 0; ni < 4; ++ni) acc[mi][ni] = f32x4{0.f, 0.f, 0.f, 0.f};
        bf16x8 bc[4];
        #pragma unroll
        for (int ni = 0; ni < 4; ++ni)
            bc[ni] = *reinterpret_cast<const bf16x8*>(
                Wt + (size_t)(w * 64 + ni * 16 + lr) * 256 + lk);
        #pragma unroll
        for (int s = 0; s < 8; ++s) {
            bf16x8 bn[4];
            if (s < 7) {
                #pragma unroll
                for (int ni = 0; ni < 4; ++ni)
                    bn[ni] = *reinterpret_cast<const bf16x8*>(
                        Wt + (size_t)(w * 64 + ni * 16 + lr) * 256 + (s + 1) * 32 + lk);
            }
            bf16x8 a0 = *reinterpret_cast<const bf16x8*>(&Al[lr][s * 32 + lk]);
            bf16x8 a1 = *reinterpret_cast<const bf16x8*>(&Al[16 + lr][s * 32 + lk]);
            #pragma unroll
            for (int ni = 0; ni < 4; ++ni) {
                acc[0][ni] = mfma16(a0, bc[ni], acc[0][ni]);
                acc[1][ni] = mfma16(a1, bc[ni], acc[1][ni]);
            }
            if (s < 7) {
                #pragma unroll
                for (int ni = 0; ni < 4; ++ni) bc[ni] = bn[ni];
            }
        }
        #pragma unroll
        for (int mi = 0; mi < 2; ++mi)
            #pragma unroll
            for (int ni = 0; ni < 4; ++ni)
                #pragma unroll
                for (int r = 0; r < 4; ++r)
                    xr[mi * 16 + q4 * 4 + r][w * 64 + ni * 16 + lr] = acc[mi][ni][r];
        __syncthreads();
        {
            float bb = g ? b2[tid] : b1[tid];
            if (g == 0) {
                for (int r = 0; r < 32; ++r)
                    xr[r][tid] += bb + bfu2f(resmat[(size_t)(m0 + r) * rstride * 256 + tid]);
            } else {
                for (int r = 0; r < 32; ++r)
                    xr[r][tid] += bb + bfu2f(Al[r][tid]);
            }
        }
        __syncthreads();
        for (int rr = w * 8; rr < w * 8 + 8; ++rr) {
            float4 v = *reinterpret_cast<const float4*>(&xr[rr][lane * 4]);
            float s1 = v.x + v.y + v.z + v.w;
            float s2 = v.x * v.x + v.y * v.y + v.z * v.z + v.w * v.w;
            #pragma unroll
            for (int off = 32; off > 0; off >>= 1) {
                s1 += __shfl_xor(s1, off);
                s2 += __shfl_xor(s2, off);
            }
            if (lane == 0) {
                float m = s1 * (1.f / 256.f);
                float var = s2 * (1.f / 256.f) - m * m;
                mrow[rr] = m;
                rrow[rr] = rsqrtf(var + LN_EPS);
            }
        }
        __syncthreads();
        if (g == 0) {
            float gg = lng1[tid], bb = lnb1[tid];
            for (int r = 0; r < 32; ++r)
                Al[r][tid] = f2bfu((xr[r][tid] - mrow[r]) * rrow[r] * gg + bb);
        } else {
            float gg = lng2[tid], bb = lnb2[tid];
            for (int r = 0; r < 32; ++r)
                out[(size_t)(m0 + r) * 256 + tid] =
                    f2bfu((xr[r][tid] - mrow[r]) * rrow[r] * gg + bb);
        }
        __syncthreads();
    }
}

// ======= k_qkv1 (unchanged) =======
__global__ __launch_bounds__(256) void k_qkv1(
    const ushort_t* __restrict__ h1, const ushort_t* __restrict__ Wt,
    const float* __restrict__ bias, ushort_t* __restrict__ outm) {
    __shared__ ushort_t Ah[64 * 256];
    __shared__ ushort_t Sh[4][32][72];
    const int tid = threadIdx.x;
    const int m0 = blockIdx.x * 64;
    const int lane = tid & 63, w = tid >> 6;
    const int lr = lane & 15, q4 = lane >> 4, lk = q4 * 8;

    #pragma unroll
    for (int i = 0; i < 8; ++i) {
        int flat = tid + i * 256;
        int row = flat >> 5, ch = flat & 31;
        *reinterpret_cast<int4*>(&Ah[row * 256 + ((ch ^ (row & 7)) * 8)]) =
            *reinterpret_cast<const int4*>(h1 + (size_t)(m0 + row) * 256 + ch * 8);
    }
    __syncthreads();

    for (int p = 0; p < 3; ++p) {
        f32x4 acc[4][4] = {};
        bf16x8 bc[4];
        #pragma unroll
        for (int ni = 0; ni < 4; ++ni)
            bc[ni] = *reinterpret_cast<const bf16x8*>(
                Wt + (size_t)(p * 256 + w * 64 + ni * 16 + lr) * 256 + lk);
        #pragma unroll
        for (int s = 0; s < 8; ++s) {
            bf16x8 bn[4];
            if (s < 7) {
                #pragma unroll
                for (int ni = 0; ni < 4; ++ni)
                    bn[ni] = *reinterpret_cast<const bf16x8*>(
                        Wt + (size_t)(p * 256 + w * 64 + ni * 16 + lr) * 256 + (s + 1) * 32 + lk);
            }
            bf16x8 a[4];
            #pragma unroll
            for (int mi = 0; mi < 4; ++mi) {
                int row = mi * 16 + lr;
                int chunk = (s * 4 + q4) ^ (row & 7);
                a[mi] = *reinterpret_cast<const bf16x8*>(&Ah[row * 256 + chunk * 8]);
            }
            #pragma unroll
            for (int mi = 0; mi < 4; ++mi)
                #pragma unroll
                for (int ni = 0; ni < 4; ++ni)
                    acc[mi][ni] = mfma16(a[mi], bc[ni], acc[mi][ni]);
            if (s < 7) {
                #pragma unroll
                for (int ni = 0; ni < 4; ++ni) bc[ni] = bn[ni];
            }
        }
        float bl[4];
        #pragma unroll
        for (int ni = 0; ni < 4; ++ni) bl[ni] = bias[p * 256 + w * 64 + ni * 16 + lr];
        const int coff = p * 256 + w * 64;
        #pragma unroll
        for (int part = 0; part < 2; ++part) {
            #pragma unroll
            for (int mi2 = 0; mi2 < 2; ++mi2) {
                int mi = part * 2 + mi2;
                #pragma unroll
                for (int ni = 0; ni < 4; ++ni)
                    #pragma unroll
                    for (int r = 0; r < 4; ++r)
                        Sh[w][mi2 * 16 + q4 * 4 + r][ni * 16 + lr] =
                            f2bfu(acc[mi][ni][r] + bl[ni]);
            }
            #pragma unroll
            for (int j = 0; j < 4; ++j) {
                int flat = lane + j * 64;
                int r32 = flat >> 3, ch = flat & 7;
                int grow = m0 + part * 32 + r32;
                *reinterpret_cast<int4*>(outm + (size_t)grow * 768 + coff + ch * 8) =
                    *reinterpret_cast<const int4*>(&Sh[w][r32][ch * 8]);
            }
        }
    }
}

// ---------------- attention: one wave per group (unchanged) ----------------
__global__ __launch_bounds__(256) void attn_wave(
    const ushort_t* __restrict__ q_all, int qld, int qoff, int qstride,
    const ushort_t* __restrict__ kv_all, int kvld, int koff, int voff,
    const int* __restrict__ kvidx, int ngroups, ushort_t* __restrict__ o_out) {
    __shared__ ushort_t KL[4][KVN][264];
    __shared__ ushort_t VL[4][KVN][264];
    const int w = threadIdx.x >> 6, lane = threadIdx.x & 63;
    const int g = blockIdx.x * 4 + w;
    if (g >= ngroups) return;

    int idx16 = 0;
    if (lane < KVN)
        idx16 = kvidx ? kvidx[g * KVN + lane] : g * SEQ + 1 + lane;

    float qv[4];
    {
        uint2 u = *reinterpret_cast<const uint2*>(
            q_all + (size_t)g * qstride * qld + qoff + lane * 4);
        qv[0] = bfu2f((ushort_t)(u.x & 0xffff));
        qv[1] = bfu2f((ushort_t)(u.x >> 16));
        qv[2] = bfu2f((ushort_t)(u.y & 0xffff));
        qv[3] = bfu2f((ushort_t)(u.y >> 16));
    }
    {
        const int r = lane & 15, qtr = lane >> 4;
        int rid = __shfl(idx16, r);
        const ushort_t* kb = kv_all + (size_t)rid * kvld + koff;
        const ushort_t* vb = kv_all + (size_t)rid * kvld + voff;
        #pragma unroll
        for (int j = 0; j < 8; ++j) {
            int c8 = (qtr * 8 + j) * 8;
            *reinterpret_cast<int4*>(&KL[w][r][c8]) = *reinterpret_cast<const int4*>(kb + c8);
            *reinterpret_cast<int4*>(&VL[w][r][c8]) = *reinterpret_cast<const int4*>(vb + c8);
        }
    }
    float att[KVN];
    #pragma unroll
    for (int k = 0; k < KVN; ++k) {
        uint2 u = *reinterpret_cast<const uint2*>(&KL[w][k][lane * 4]);
        float p = qv[0] * bfu2f((ushort_t)(u.x & 0xffff))
                + qv[1] * bfu2f((ushort_t)(u.x >> 16))
                + qv[2] * bfu2f((ushort_t)(u.y & 0xffff))
                + qv[3] * bfu2f((ushort_t)(u.y >> 16));
        p += __shfl_xor(p, 1);
        p += __shfl_xor(p, 2);
        p += __shfl_xor(p, 4);
        att[k] = p * 0.17677669529663687f;
    }
    float m = att[0];
    #pragma unroll
    for (int k = 1; k < KVN; ++k) m = fmaxf(m, att[k]);
    float sum = 0.f;
    #pragma unroll
    for (int k = 0; k < KVN; ++k) { att[k] = __expf(att[k] - m); sum += att[k]; }
    float inv = 1.f / sum;
    float o[4] = {0.f, 0.f, 0.f, 0.f};
    #pragma unroll
    for (int k = 0; k < KVN; ++k) {
        uint2 u = *reinterpret_cast<const uint2*>(&VL[w][k][lane * 4]);
        float a = att[k] * inv;
        o[0] += a * bfu2f((ushort_t)(u.x & 0xffff));
        o[1] += a * bfu2f((ushort_t)(u.x >> 16));
        o[2] += a * bfu2f((ushort_t)(u.y & 0xffff));
        o[3] += a * bfu2f((ushort_t)(u.y >> 16));
    }
    uint2 r;
    r.x = (unsigned)f2bfu(o[0]) | ((unsigned)f2bfu(o[1]) << 16);
    r.y = (unsigned)f2bfu(o[2]) | ((unsigned)f2bfu(o[3]) << 16);
    *reinterpret_cast<uint2*>(o_out + (size_t)g * 256 + lane * 4) = r;
}

// ---------------- output head (unchanged) ----------------
__global__ __launch_bounds__(64) void k_out(
    const ushort_t* __restrict__ h2, const float* __restrict__ W_out,
    const float* __restrict__ b_out, float* __restrict__ out) {
    const int b = blockIdx.x, j = threadIdx.x;
    __shared__ float xr[HDIM];
    for (int k = j; k < HDIM; k += 64) xr[k] = bfu2f(h2[(size_t)b * HDIM + k]);
    __syncthreads();
    float logit = -1e30f;
    if (j < OUTD) {
        float acc = b_out[j];
        for (int k = 0; k < HDIM; ++k) acc += xr[k] * W_out[k * OUTD + j];
        logit = acc;
    }
    float m = logit;
    #pragma unroll
    for (int off = 32; off > 0; off >>= 1) m = fmaxf(m, __shfl_xor(m, off));
    float e = (j < OUTD) ? __expf(logit - m) : 0.f;
    float s = e;
    #pragma unroll
    for (int off = 32; off > 0; off >>= 1) s += __shfl_xor(s, off);
    if (j < OUTD) out[(size_t)b * OUTD + j] = e / s;
}

extern "C" void kernel_launch(void* const* d_in, const int* in_sizes, int n_in,
                              void* d_out, int out_size, void* d_ws, size_t ws_size,
                              hipStream_t stream) {
    const float* nf    = (const float*)d_in[0];
    const int*   batch = (const int*)d_in[1];
    const int*   nbr2  = (const int*)d_in[2];
    const int*   nbr1  = (const int*)d_in[3];
    const float* W_in  = (const float*)d_in[4];
    const float* b_in  = (const float*)d_in[5];
    const float* Wqkv  = (const float*)d_in[6];
    const float* bqkv  = (const float*)d_in[7];
    const float* Wo    = (const float*)d_in[8];
    const float* bo    = (const float*)d_in[9];
    const float* Wf    = (const float*)d_in[10];
    const float* bf    = (const float*)d_in[11];
    const float* ln_g  = (const float*)d_in[12];
    const float* ln_b  = (const float*)d_in[13];
    const float* W_out = (const float*)d_in[14];
    const float* b_out = (const float*)d_in[15];
    float* out = (float*)d_out;
    char* ws = (char*)d_ws;

    ushort_t* hq   = (ushort_t*)(ws + OFF_HQ);
    ushort_t* kv0  = (ushort_t*)(ws + OFF_KV0);
    ushort_t* q0   = (ushort_t*)(ws + OFF_Q0);
    ushort_t* o0   = (ushort_t*)(ws + OFF_O0);
    ushort_t* h1   = (ushort_t*)(ws + OFF_H1);
    ushort_t* qkv1 = (ushort_t*)(ws + OFF_QKV1);
    ushort_t* o1   = (ushort_t*)(ws + OFF_O1);
    ushort_t* h2   = (ushort_t*)(ws + OFF_H2);
    const int* ids1 = (const int*)(ws + OFF_IDS);

    hipLaunchKernelGGL(k_prep, dim3(256, 13), dim3(256), 0, stream,
                       W_in, Wqkv, Wo, Wf, bqkv, batch, nbr2, ws);
    hipLaunchKernelGGL(k_fused, dim3(NKVBLK + NHQBLK), dim3(256), 0, stream,
                       nf, (const ushort_t*)(ws + OFF_WTIN), b_in,
                       (const ushort_t*)(ws + OFF_WKV0),
                       (const ushort_t*)(ws + OFF_WQ0), bqkv, ids1,
                       kv0, hq, q0);
    // A0
    hipLaunchKernelGGL(attn_wave, dim3(N1 / 4), dim3(256), 0, stream,
                       q0, 256, 0, 1, kv0, 512, 0, 256, nbr1, N1, o0);
    // FFN0
    hipLaunchKernelGGL(k_ffn, dim3(N1 / 32), dim3(256), 0, stream,
                       o0, (const ushort_t*)(ws + OFF_WO0), bo,
                       hq, 1, ln_g, ln_b,
                       (const ushort_t*)(ws + OFF_WF0), bf,
                       ln_g + 256, ln_b + 256, h1);
    // G5
    hipLaunchKernelGGL(k_qkv1, dim3(N1 / 64), dim3(256), 0, stream,
                       h1, (const ushort_t*)(ws + OFF_WKVQ1),
                       (const float*)(ws + OFF_B1), qkv1);
    // A1
    hipLaunchKernelGGL(attn_wave, dim3(B_SZ / 4), dim3(256), 0, stream,
                       qkv1, 768, 512, 17, qkv1, 768, 0, 256,
                       (const int*)nullptr, B_SZ, o1);
    // FFN1
    hipLaunchKernelGGL(k_ffn, dim3(B_SZ / 32), dim3(256), 0, stream,
                       o1, (const ushort_t*)(ws + OFF_WO1), bo + 256,
                       h1, 17, ln_g + 512, ln_b + 512,
                       (const ushort_t*)(ws + OFF_WF1), bf + 256,
                       ln_g + 768, ln_b + 768, h2);
    hipLaunchKernelGGL(k_out, dim3(B_SZ), dim3(64), 0, stream,
                       h2, W_out, b_out, out);
}